// Round 8
// baseline (91.035 us; speedup 1.0000x reference)
//
#include <hip/hip_runtime.h>
#include <hip/hip_bf16.h>

typedef unsigned short u16;
typedef __bf16 bf16x8 __attribute__((ext_vector_type(8)));
typedef float f32x4 __attribute__((ext_vector_type(4)));

__device__ __forceinline__ u16 f2bf(float f) {
    unsigned u = __builtin_bit_cast(unsigned, f);
    unsigned r = (u + 0x7fffu + ((u >> 16) & 1u)) >> 16;
    return (u16)r;
}

#define GLDS16(g, l)                                                      \
    __builtin_amdgcn_global_load_lds(                                     \
        (const __attribute__((address_space(1))) void*)(g),               \
        (__attribute__((address_space(3))) void*)(l), 16, 0, 0)

// ---- fused prep ----
// blocks [0,3072): flat f32->bf16 convert of x (1048576 f4) + V0 (524288 f4),
//                  2 float4/thread.
// blocks [3072,4608): 64x64 transpose+convert tiles: V1 (2048^2) -> V1t,
//                  V2 (2048x1024) -> V2t. One tile per block.
__global__ __launch_bounds__(256) void prep(const float* __restrict__ x,
                                            u16* __restrict__ xb,
                                            const float* __restrict__ V0,
                                            u16* __restrict__ V0b,
                                            const float* __restrict__ V1,
                                            u16* __restrict__ V1t,
                                            const float* __restrict__ V2,
                                            u16* __restrict__ V2t) {
    __shared__ float tile[64][65];
    const int b = blockIdx.x, t = threadIdx.x;
    if (b < 3072) {
        int i0 = b * 512 + t;
#pragma unroll
        for (int p = 0; p < 2; ++p) {
            int i = i0 + p * 256;
            const float* s; u16* d; int j;
            if (i < 1048576) { s = x; d = xb; j = i; }
            else { s = V0; d = V0b; j = i - 1048576; }
            float4 v = ((const float4*)s)[j];
            ushort4 o; o.x = f2bf(v.x); o.y = f2bf(v.y); o.z = f2bf(v.z); o.w = f2bf(v.w);
            ((ushort4*)d)[j] = o;
        }
        return;
    }
    const int b2 = b - 3072;
    const float* src; u16* dst; int C, rt, ct;
    if (b2 < 1024) { src = V1; dst = V1t; C = 2048; rt = b2 >> 5; ct = b2 & 31; }
    else { int b3 = b2 - 1024; src = V2; dst = V2t; C = 1024; rt = b3 >> 4; ct = b3 & 15; }
    const int r0 = rt * 64, c0 = ct * 64;
    const int trow = t >> 4;       // 0..15
    const int tc4 = t & 15;        // float4 / ushort4 chunk index

#pragma unroll
    for (int p = 0; p < 4; ++p) {
        int r = p * 16 + trow;
        float4 v = *(const float4*)&src[(size_t)(r0 + r) * C + c0 + tc4 * 4];
        tile[r][tc4 * 4 + 0] = v.x; tile[r][tc4 * 4 + 1] = v.y;
        tile[r][tc4 * 4 + 2] = v.z; tile[r][tc4 * 4 + 3] = v.w;
    }
    __syncthreads();
#pragma unroll
    for (int p = 0; p < 4; ++p) {
        int c = p * 16 + trow;
        int rr = tc4 * 4;
        ushort4 o;
        o.x = f2bf(tile[rr + 0][c]); o.y = f2bf(tile[rr + 1][c]);
        o.z = f2bf(tile[rr + 2][c]); o.w = f2bf(tile[rr + 3][c]);
        *(ushort4*)&dst[(size_t)(c0 + c) * 2048 + r0 + rr] = o;
    }
}

// ---------------- bf16 GEMM: C = A(MxK) * Bt(NxK)^T, no split-K ----------------
// Tile BM x 64, BK=32, 8 waves (2x4), per-wave (BM/2) x 16, acc[BM/32].
// Double-buffered LDS, one vmcnt(0)+s_barrier per K-step.
template <int BM, int F32OUT>
__global__ __launch_bounds__(512) void gemm_bt(const u16* __restrict__ A,
                                               const u16* __restrict__ Bt,
                                               void* __restrict__ Cv,
                                               int N, int Ktot) {
    constexpr int MF = BM / 32;           // m-fragments per wave
    __shared__ u16 sA[2][BM * 32];
    __shared__ u16 sB[2][64 * 32];

    const int t = threadIdx.x;
    const int lane = t & 63;
    const int w = t >> 6;                 // 0..7
    const int wr = w >> 2, wc = w & 3;
    const int l15 = lane & 15, l4 = lane >> 4;
    const int row0 = blockIdx.y * BM, col0 = blockIdx.x * 64;

    f32x4 acc[MF];
#pragma unroll
    for (int m = 0; m < MF; ++m) acc[m] = (f32x4){0.f, 0.f, 0.f, 0.f};

    // staging segment assignment (16B segs: seg -> row seg>>2, k-chunk (seg&3)*8)
    // BM=128: A segs 512 (all threads), B segs 256 (t<256).
    // BM=64:  A segs 256 (t<256),       B segs 256 (t>=256).
    const bool doA = (BM == 128) ? true : (t < 256);
    const bool doB = (BM == 128) ? (t < 256) : (t >= 256);
    const int segA = (BM == 128) ? t : t;                 // valid when doA
    const int segB = (BM == 128) ? t : t - 256;           // valid when doB

    const u16* Abase = A  + (size_t)(row0 + (segA >> 2)) * Ktot + (segA & 3) * 8;
    const u16* Bbase = Bt + (size_t)(col0 + ((segB & 255) >> 2)) * Ktot + (segB & 3) * 8;

    // prologue: stage K-tile 0 into buffer 0
    if (doA) GLDS16(Abase, &sA[0][segA * 8]);
    if (doB) GLDS16(Bbase, &sB[0][(segB & 255) * 8]);
    asm volatile("s_waitcnt vmcnt(0)" ::: "memory");
    __builtin_amdgcn_s_barrier();

    const int nK = Ktot >> 5;
    int cur = 0;
    for (int kt = 0; kt < nK; ++kt) {
        if (kt + 1 < nK) {
            if (doA) GLDS16(Abase + (kt + 1) * 32, &sA[cur ^ 1][segA * 8]);
            if (doB) GLDS16(Bbase + (kt + 1) * 32, &sB[cur ^ 1][(segB & 255) * 8]);
        }

        bf16x8 af[MF], bfr;
#pragma unroll
        for (int m = 0; m < MF; ++m)
            af[m] = *(const bf16x8*)&sA[cur][(wr * (BM / 2) + m * 16 + l15) * 32 + l4 * 8];
        bfr = *(const bf16x8*)&sB[cur][(wc * 16 + l15) * 32 + l4 * 8];
#pragma unroll
        for (int m = 0; m < MF; ++m)
            acc[m] = __builtin_amdgcn_mfma_f32_16x16x32_bf16(af[m], bfr, acc[m], 0, 0, 0);

        asm volatile("s_waitcnt vmcnt(0)" ::: "memory");
        __builtin_amdgcn_s_barrier();
        cur ^= 1;
    }

    // epilogue: D row = (lane>>4)*4 + j, col = lane&15  [verified layout]
#pragma unroll
    for (int m = 0; m < MF; ++m) {
        int r = row0 + wr * (BM / 2) + m * 16 + l4 * 4;
        int c = col0 + wc * 16 + l15;
#pragma unroll
        for (int j = 0; j < 4; ++j) {
            if (F32OUT) ((float*)Cv)[(size_t)(r + j) * N + c] = acc[m][j];
            else        ((u16*)Cv)[(size_t)(r + j) * N + c] = f2bf(acc[m][j]);
        }
    }
}

// dims: x(4096,1024)  V0(1024,2048) V1(2048,2048) V2(2048,1024)
// out = x @ ((V0@V1)@V2):
//   P1  = V0@V1          (1024x2048 bf16)  grid (32,8)
//   P2t = V2^T @ P1^T    (1024x1024 bf16)  grid (16,16)
//   G   = x @ P2         (4096x1024 f32)   grid (16,32) -> d_out
// d_in order: x, V0, W0, V1, W1, V2, W2
extern "C" void kernel_launch(void* const* d_in, const int* in_sizes, int n_in,
                              void* d_out, int out_size, void* d_ws, size_t ws_size,
                              hipStream_t stream) {
    const float* x  = (const float*)d_in[0];
    const float* V0 = (const float*)d_in[1];
    const float* V1 = (const float*)d_in[3];
    const float* V2 = (const float*)d_in[5];

    char* ws = (char*)d_ws;
    u16* xb  = (u16*)(ws);                          // 8 MB  (4096x1024)
    u16* V0b = (u16*)(ws + ((size_t)8 << 20));      // 4 MB  (1024x2048, row-major)
    u16* V1t = (u16*)(ws + ((size_t)12 << 20));     // 8 MB  (2048x2048, = V1^T)
    u16* V2t = (u16*)(ws + ((size_t)20 << 20));     // 4 MB  (1024x2048, = V2^T)
    u16* P1  = (u16*)(ws + ((size_t)24 << 20));     // 4 MB  (1024x2048)
    u16* P2t = (u16*)(ws + ((size_t)28 << 20));     // 2 MB  (1024x1024)

    prep<<<4608, 256, 0, stream>>>(x, xb, V0, V0b, V1, V1t, V2, V2t);

    // P1 = V0 @ V1 : M=1024, N=2048, K=2048
    gemm_bt<128, 0><<<dim3(32, 8), 512, 0, stream>>>(V0b, V1t, P1, 2048, 2048);
    // P2t = V2^T @ P1^T : M=1024, N=1024, K=2048
    gemm_bt<64, 0><<<dim3(16, 16), 512, 0, stream>>>(V2t, P1, P2t, 1024, 2048);
    // G = x @ P2 : M=4096, N=1024, K=1024
    gemm_bt<128, 1><<<dim3(16, 32), 512, 0, stream>>>(xb, P2t, d_out, 1024, 1024);
}